// Round 1
// baseline (894.792 us; speedup 1.0000x reference)
//
#include <hip/hip_runtime.h>

// TransformerBlock fused pipeline for MI355X (gfx950).
// SEQ=2048, D_MODEL=2048, H=16, DK=DV=128, DFF=8192. fp32 in/out.
//
// Numerics: attention score path (x->Q/K->QK^T) uses 3-pass split-bf16
// (hi/lo) because softmax at score-std ~2000 is near-argmax: single-bf16
// score error sigma~4.5 flips ~140 rows => absmax ~0.3 > 0.109 threshold.
// Everything else is single-pass bf16 MFMA (errors ~0.2% relative, washed
// by LayerNorm). LN/softmax/residual in fp32.

typedef __bf16 bf16;
typedef __attribute__((ext_vector_type(8))) __bf16 bf16x8;
typedef __attribute__((ext_vector_type(4))) __bf16 bf16x4;
typedef __attribute__((ext_vector_type(4))) float f32x4;

#define MFMA(a, b, c) __builtin_amdgcn_mfma_f32_16x16x32_bf16((a), (b), (c), 0, 0, 0)
#define NEG_INF (-3.402823466e38f)

__device__ __forceinline__ void cp16(void* lds, const void* g) {
  // async global->LDS, 16B per lane; LDS dst is wave-uniform base + lane*16
  __builtin_amdgcn_global_load_lds(
      (const __attribute__((address_space(1))) unsigned int*)g,
      (__attribute__((address_space(3))) unsigned int*)lds, 16, 0, 0);
}

// ---------------- converts ----------------

// x fp32 -> bf16 hi + bf16 lo (residual). 4 elems/thread, exact grid.
__global__ void k_split_x(const float* __restrict__ x, bf16* __restrict__ xh,
                          bf16* __restrict__ xl) {
  int i = blockIdx.x * 256 + threadIdx.x;
  f32x4 v = ((const f32x4*)x)[i];
  bf16x4 h, l;
#pragma unroll
  for (int j = 0; j < 4; ++j) {
    bf16 hi = (bf16)v[j];
    h[j] = hi;
    l[j] = (bf16)(v[j] - (float)hi);
  }
  ((bf16x4*)xh)[i] = h;
  ((bf16x4*)xl)[i] = l;
}

// Tiled transpose + convert: in fp32 [R][C] (+z*R*C) -> out bf16 [C][R] (+z*R*C).
template <bool SPLIT>
__global__ void k_tcvt(const float* __restrict__ in, bf16* __restrict__ oh,
                       bf16* __restrict__ ol, int R, int C) {
  __shared__ float t[64][65];
  long zoff = (long)blockIdx.z * R * C;
  int c0 = blockIdx.x * 64, r0 = blockIdx.y * 64;
  int cc = threadIdx.x & 63, rr = threadIdx.x >> 6;
#pragma unroll
  for (int i = 0; i < 16; ++i) {
    int r = i * 4 + rr;
    t[r][cc] = in[zoff + (long)(r0 + r) * C + c0 + cc];
  }
  __syncthreads();
#pragma unroll
  for (int i = 0; i < 16; ++i) {
    int orow = i * 4 + rr;
    float v = t[cc][orow];
    long oidx = zoff + (long)(c0 + orow) * R + r0 + cc;
    bf16 hi = (bf16)v;
    oh[oidx] = hi;
    if (SPLIT) ol[oidx] = (bf16)(v - (float)hi);
  }
}

// ---------------- GEMM: C[M,N] = A[M,K] @ B[N,K]^T ----------------
// m97 structure: 128x128 tile, BK=32, 4 waves (2x2), global_load_lds w=16.
// EPI: 0 = fp32 out (+bias if non-null), 1 = bf16 out, 2 = relu(v+bias) bf16.
template <int EPI>
__global__ __launch_bounds__(256, 3) void k_gemm_bt(
    const bf16* __restrict__ A, const bf16* __restrict__ B,
    float* __restrict__ Cf, bf16* __restrict__ Cb,
    const float* __restrict__ bias, int M, int N, int K) {
  __shared__ bf16 sA[4096], sB[4096];
  const int tid = threadIdx.x, w = tid >> 6, l = tid & 63;
  const int l16 = l & 15, lg = l >> 4;
  const int wr = w >> 1, wc = w & 1;
  const long bm0 = (long)blockIdx.y * 128, bn0 = (long)blockIdx.x * 128;
  f32x4 acc[4][4];
#pragma unroll
  for (int m = 0; m < 4; ++m)
#pragma unroll
    for (int n = 0; n < 4; ++n)
#pragma unroll
      for (int j = 0; j < 4; ++j) acc[m][n][j] = 0.f;

  for (int kt = 0; kt < K; kt += 32) {
    __syncthreads();
#pragma unroll
    for (int i = 0; i < 2; ++i) {
      int c = (w * 2 + i) * 64 + l;  // 0..511 chunk of 16B
      int row = c >> 2, seg = c & 3;
      cp16(&sA[(w * 2 + i) * 512], &A[(bm0 + row) * K + kt + seg * 8]);
      cp16(&sB[(w * 2 + i) * 512], &B[(bn0 + row) * K + kt + seg * 8]);
    }
    __syncthreads();
    bf16x8 a[4], b[4];
#pragma unroll
    for (int m = 0; m < 4; ++m)
      a[m] = *(const bf16x8*)&sA[(wr * 64 + m * 16 + l16) * 32 + lg * 8];
#pragma unroll
    for (int n = 0; n < 4; ++n)
      b[n] = *(const bf16x8*)&sB[(wc * 64 + n * 16 + l16) * 32 + lg * 8];
#pragma unroll
    for (int m = 0; m < 4; ++m)
#pragma unroll
      for (int n = 0; n < 4; ++n)
        acc[m][n] = MFMA(a[m], b[n], acc[m][n]);
  }
  // epilogue: C/D layout col=lane&15, row=(lane>>4)*4+j (m89-verified)
#pragma unroll
  for (int m = 0; m < 4; ++m)
#pragma unroll
    for (int n = 0; n < 4; ++n) {
      long col = bn0 + wc * 64 + n * 16 + l16;
      float bv = (bias != nullptr) ? bias[col] : 0.f;
#pragma unroll
      for (int j = 0; j < 4; ++j) {
        long row = bm0 + wr * 64 + m * 16 + lg * 4 + j;
        float v = acc[m][n][j];
        if (EPI == 0) {
          Cf[row * N + col] = v + bv;
        } else if (EPI == 1) {
          Cb[row * N + col] = (bf16)v;
        } else {
          v = fmaxf(v + bv, 0.f);
          Cb[row * N + col] = (bf16)v;
        }
      }
    }
}

// Split-precision GEMM: C = Ah.Bh^T + Ah.Bl^T + Al.Bh^T, output split hi/lo.
__global__ __launch_bounds__(256, 2) void k_gemm_split3(
    const bf16* __restrict__ Ah, const bf16* __restrict__ Al,
    const bf16* __restrict__ Bh, const bf16* __restrict__ Bl,
    bf16* __restrict__ Ch, bf16* __restrict__ Cl,
    int M, int N, int K, float scale) {
  __shared__ bf16 sAh[4096], sAl[4096], sBh[4096], sBl[4096];
  const int tid = threadIdx.x, w = tid >> 6, l = tid & 63;
  const int l16 = l & 15, lg = l >> 4;
  const int wr = w >> 1, wc = w & 1;
  const long bm0 = (long)blockIdx.y * 128, bn0 = (long)blockIdx.x * 128;
  f32x4 acc[4][4];
#pragma unroll
  for (int m = 0; m < 4; ++m)
#pragma unroll
    for (int n = 0; n < 4; ++n)
#pragma unroll
      for (int j = 0; j < 4; ++j) acc[m][n][j] = 0.f;

  for (int kt = 0; kt < K; kt += 32) {
    __syncthreads();
#pragma unroll
    for (int i = 0; i < 2; ++i) {
      int c = (w * 2 + i) * 64 + l;
      int row = c >> 2, seg = c & 3;
      long ao = (bm0 + row) * K + kt + seg * 8;
      long bo = (bn0 + row) * K + kt + seg * 8;
      int db = (w * 2 + i) * 512;
      cp16(&sAh[db], &Ah[ao]);
      cp16(&sAl[db], &Al[ao]);
      cp16(&sBh[db], &Bh[bo]);
      cp16(&sBl[db], &Bl[bo]);
    }
    __syncthreads();
    bf16x8 ah[4], al[4], bh[4], bl[4];
#pragma unroll
    for (int m = 0; m < 4; ++m) {
      int off = (wr * 64 + m * 16 + l16) * 32 + lg * 8;
      ah[m] = *(const bf16x8*)&sAh[off];
      al[m] = *(const bf16x8*)&sAl[off];
    }
#pragma unroll
    for (int n = 0; n < 4; ++n) {
      int off = (wc * 64 + n * 16 + l16) * 32 + lg * 8;
      bh[n] = *(const bf16x8*)&sBh[off];
      bl[n] = *(const bf16x8*)&sBl[off];
    }
#pragma unroll
    for (int m = 0; m < 4; ++m)
#pragma unroll
      for (int n = 0; n < 4; ++n) {
        acc[m][n] = MFMA(ah[m], bh[n], acc[m][n]);
        acc[m][n] = MFMA(ah[m], bl[n], acc[m][n]);
        acc[m][n] = MFMA(al[m], bh[n], acc[m][n]);
      }
  }
#pragma unroll
  for (int m = 0; m < 4; ++m)
#pragma unroll
    for (int n = 0; n < 4; ++n) {
      long col = bn0 + wc * 64 + n * 16 + l16;
#pragma unroll
      for (int j = 0; j < 4; ++j) {
        long row = bm0 + wr * 64 + m * 16 + lg * 4 + j;
        float v = acc[m][n][j] * scale;
        bf16 hi = (bf16)v;
        Ch[row * N + col] = hi;
        Cl[row * N + col] = (bf16)(v - (float)hi);
      }
    }
}

// ---------------- flash attention ----------------
// Block = (q-block of 128 rows, head). 4 waves, each owns 32 q-rows.
// Q hi/lo in registers; K hi/lo + V^T staged in LDS (XOR-swizzled, rule #21:
// inverse-swizzled global source + swizzled ds_read). 3-pass QK^T, online
// softmax in fp32, P->LDS (bf16, swizzled) for A-frag transpose, PV MFMA.
__global__ __launch_bounds__(256, 2) void k_flash(
    const bf16* __restrict__ Qh, const bf16* __restrict__ Ql,
    const bf16* __restrict__ Kh, const bf16* __restrict__ Kl,
    const bf16* __restrict__ Vt, bf16* __restrict__ Oc) {
  __shared__ bf16 sm[32768];  // 64 KB: Kh[64][128] Kl[64][128] Vt[128][64] P[128][64]
  bf16* sKh = sm;
  bf16* sKl = sm + 8192;
  bf16* sVt = sm + 16384;
  bf16* sP = sm + 24576;
  const int tid = threadIdx.x, w = tid >> 6, l = tid & 63;
  const int l16 = l & 15, lg = l >> 4;
  const int head = blockIdx.y;
  const long q0 = (long)blockIdx.x * 128;

  // Q fragments in registers: rows w*32+m*16+l16, k = kk*32+lg*8
  bf16x8 qh_r[4][2], ql_r[4][2];
#pragma unroll
  for (int kk = 0; kk < 4; ++kk)
#pragma unroll
    for (int m = 0; m < 2; ++m) {
      long off = (q0 + w * 32 + m * 16 + l16) * 2048 + head * 128 + kk * 32 + lg * 8;
      qh_r[kk][m] = *(const bf16x8*)&Qh[off];
      ql_r[kk][m] = *(const bf16x8*)&Ql[off];
    }

  f32x4 acc_o[2][8];
#pragma unroll
  for (int m = 0; m < 2; ++m)
#pragma unroll
    for (int n = 0; n < 8; ++n)
#pragma unroll
      for (int j = 0; j < 4; ++j) acc_o[m][n][j] = 0.f;
  float mrow[2][4], lrow[2][4];
#pragma unroll
  for (int m = 0; m < 2; ++m)
#pragma unroll
    for (int j = 0; j < 4; ++j) {
      mrow[m][j] = NEG_INF;
      lrow[m][j] = 0.f;
    }

  for (int t0 = 0; t0 < 2048; t0 += 64) {
    __syncthreads();
    // stage K hi/lo [64][128] and V^T [128][64]; source pre-swizzled
#pragma unroll
    for (int i = 0; i < 4; ++i) {
      int c = (w * 4 + i) * 64 + l;  // 0..1023
      int rk = c >> 4, sk = (c & 15) ^ (rk & 7);
      long ko = (long)(t0 + rk) * 2048 + head * 128 + sk * 8;
      int db = (w * 4 + i) * 512;
      cp16(&sKh[db], &Kh[ko]);
      cp16(&sKl[db], &Kl[ko]);
      int rv = c >> 3, sv = (c & 7) ^ (rv & 7);
      long vo = (long)(head * 128 + rv) * 2048 + t0 + sv * 8;
      cp16(&sVt[db], &Vt[vo]);
    }
    __syncthreads();

    // QK^T, 3-pass split (hi.hi + hi.lo + lo.hi)
    f32x4 s[2][4];
#pragma unroll
    for (int m = 0; m < 2; ++m)
#pragma unroll
      for (int n = 0; n < 4; ++n)
#pragma unroll
        for (int j = 0; j < 4; ++j) s[m][n][j] = 0.f;
#pragma unroll
    for (int kk = 0; kk < 4; ++kk) {
      bf16x8 bh[4], bl[4];
#pragma unroll
      for (int n = 0; n < 4; ++n) {
        int r = n * 16 + l16;
        int byo = r * 256 + (((kk * 4 + lg) ^ (r & 7)) << 4);
        bh[n] = *(const bf16x8*)((const char*)sKh + byo);
        bl[n] = *(const bf16x8*)((const char*)sKl + byo);
      }
#pragma unroll
      for (int m = 0; m < 2; ++m)
#pragma unroll
        for (int n = 0; n < 4; ++n) {
          s[m][n] = MFMA(qh_r[kk][m], bh[n], s[m][n]);
          s[m][n] = MFMA(qh_r[kk][m], bl[n], s[m][n]);
          s[m][n] = MFMA(ql_r[kk][m], bh[n], s[m][n]);
        }
    }

    // online softmax: row = w*32 + m*16 + lg*4 + j, cols = n*16 + l16
#pragma unroll
    for (int m = 0; m < 2; ++m)
#pragma unroll
      for (int j = 0; j < 4; ++j) {
        float mx = fmaxf(fmaxf(s[m][0][j], s[m][1][j]), fmaxf(s[m][2][j], s[m][3][j]));
        mx = fmaxf(mx, __shfl_xor(mx, 1));
        mx = fmaxf(mx, __shfl_xor(mx, 2));
        mx = fmaxf(mx, __shfl_xor(mx, 4));
        mx = fmaxf(mx, __shfl_xor(mx, 8));
        float mo = mrow[m][j];
        float mn = fmaxf(mo, mx);
        mrow[m][j] = mn;
        float f = __expf(mo - mn);
        int prow = w * 32 + m * 16 + lg * 4 + j;
        float ssum = 0.f;
#pragma unroll
        for (int n = 0; n < 4; ++n) {
          float p = __expf(s[m][n][j] - mn);
          ssum += p;
          int byo = prow * 128 + (((n * 16 + l16) * 2) ^ ((prow & 7) << 4));
          *(bf16*)((char*)sP + byo) = (bf16)p;
        }
        ssum += __shfl_xor(ssum, 1);
        ssum += __shfl_xor(ssum, 2);
        ssum += __shfl_xor(ssum, 4);
        ssum += __shfl_xor(ssum, 8);
        lrow[m][j] = lrow[m][j] * f + ssum;
#pragma unroll
        for (int n = 0; n < 8; ++n) acc_o[m][n][j] *= f;
      }

    // PV: acc_o += P[32s x 64t] @ V[64t x 128v] (per wave; own P rows only)
#pragma unroll
    for (int kk = 0; kk < 2; ++kk) {
      bf16x8 pa[2], bv[8];
#pragma unroll
      for (int m = 0; m < 2; ++m) {
        int r = w * 32 + m * 16 + l16;
        int byo = r * 128 + (((kk * 4 + lg) ^ (r & 7)) << 4);
        pa[m] = *(const bf16x8*)((const char*)sP + byo);
      }
#pragma unroll
      for (int n = 0; n < 8; ++n) {
        int r = n * 16 + l16;
        int byo = r * 128 + (((kk * 4 + lg) ^ (r & 7)) << 4);
        bv[n] = *(const bf16x8*)((const char*)sVt + byo);
      }
#pragma unroll
      for (int m = 0; m < 2; ++m)
#pragma unroll
        for (int n = 0; n < 8; ++n)
          acc_o[m][n] = MFMA(pa[m], bv[n], acc_o[m][n]);
    }
  }

  // normalize + write concat[s][head*128 + v]
#pragma unroll
  for (int m = 0; m < 2; ++m)
#pragma unroll
    for (int j = 0; j < 4; ++j) {
      float rinv = 1.f / lrow[m][j];
      long row = q0 + w * 32 + m * 16 + lg * 4 + j;
#pragma unroll
      for (int n = 0; n < 8; ++n)
        Oc[row * 2048 + head * 128 + n * 16 + l16] = (bf16)(acc_o[m][n][j] * rinv);
    }
}

// ---------------- residual + LayerNorm ----------------
// One row (2048) per block; o32 fp32 always, obf bf16 optional.
__global__ __launch_bounds__(256) void k_add_ln(
    const float* __restrict__ a, const float* __restrict__ b,
    const float* __restrict__ g, const float* __restrict__ be,
    float* __restrict__ o32, bf16* __restrict__ obf) {
  __shared__ float red[8];
  int row = blockIdx.x, tid = threadIdx.x;
  const float* pa = a + (long)row * 2048;
  const float* pb = b + (long)row * 2048;
  f32x4 v[2];
  float sum = 0.f, sq = 0.f;
#pragma unroll
  for (int i = 0; i < 2; ++i) {
    int idx = i * 1024 + tid * 4;
    f32x4 va = *(const f32x4*)(pa + idx);
    f32x4 vb = *(const f32x4*)(pb + idx);
    v[i] = va + vb;
#pragma unroll
    for (int j = 0; j < 4; ++j) {
      sum += v[i][j];
      sq += v[i][j] * v[i][j];
    }
  }
#pragma unroll
  for (int o = 1; o < 64; o <<= 1) {
    sum += __shfl_xor(sum, o);
    sq += __shfl_xor(sq, o);
  }
  int w = tid >> 6;
  if ((tid & 63) == 0) {
    red[w * 2] = sum;
    red[w * 2 + 1] = sq;
  }
  __syncthreads();
  sum = red[0] + red[2] + red[4] + red[6];
  sq = red[1] + red[3] + red[5] + red[7];
  float mu = sum * (1.f / 2048.f);
  float var = sq * (1.f / 2048.f) - mu * mu;
  float rs = rsqrtf(var + 1e-5f);
#pragma unroll
  for (int i = 0; i < 2; ++i) {
    int idx = i * 1024 + tid * 4;
    f32x4 vg = *(const f32x4*)(g + idx);
    f32x4 vb = *(const f32x4*)(be + idx);
    f32x4 o;
#pragma unroll
    for (int j = 0; j < 4; ++j) o[j] = (v[i][j] - mu) * rs * vg[j] + vb[j];
    *(f32x4*)(o32 + (long)row * 2048 + idx) = o;
    if (obf != nullptr) {
      bf16x4 ob;
#pragma unroll
      for (int j = 0; j < 4; ++j) ob[j] = (bf16)o[j];
      *(bf16x4*)(obf + (long)row * 2048 + idx) = ob;
    }
  }
}

// ---------------- launch ----------------
extern "C" void kernel_launch(void* const* d_in, const int* in_sizes, int n_in,
                              void* d_out, int out_size, void* d_ws, size_t ws_size,
                              hipStream_t stream) {
  const float* x    = (const float*)d_in[0];
  const float* wq   = (const float*)d_in[1];
  const float* wk   = (const float*)d_in[2];
  const float* wv   = (const float*)d_in[3];
  const float* wp   = (const float*)d_in[4];
  const float* g1   = (const float*)d_in[5];
  const float* b1   = (const float*)d_in[6];
  const float* fc1w = (const float*)d_in[7];
  const float* fc1b = (const float*)d_in[8];
  const float* fc2w = (const float*)d_in[9];
  const float* fc2b = (const float*)d_in[10];
  const float* g2   = (const float*)d_in[11];
  const float* b2   = (const float*)d_in[12];
  float* out = (float*)d_out;

  char* ws = (char*)d_ws;
  const size_t MB = 1024 * 1024;
  if (ws_size < 216 * MB) return;  // need 216MB scratch

  bf16* xh   = (bf16*)(ws + 0 * MB);
  bf16* xl   = (bf16*)(ws + 8 * MB);
  bf16* wqh  = (bf16*)(ws + 16 * MB);
  bf16* wql  = (bf16*)(ws + 24 * MB);
  bf16* wkh  = (bf16*)(ws + 32 * MB);
  bf16* wkl  = (bf16*)(ws + 40 * MB);
  bf16* wvt  = (bf16*)(ws + 48 * MB);
  bf16* wpt  = (bf16*)(ws + 56 * MB);
  bf16* fc1t = (bf16*)(ws + 64 * MB);   // 32MB
  bf16* fc2t = (bf16*)(ws + 96 * MB);   // 32MB
  bf16* qh   = (bf16*)(ws + 128 * MB);
  bf16* ql   = (bf16*)(ws + 136 * MB);
  bf16* kh   = (bf16*)(ws + 144 * MB);
  bf16* kl   = (bf16*)(ws + 152 * MB);
  bf16* ff1  = (bf16*)(ws + 128 * MB);  // aliases qh..kl (dead after flash)
  bf16* vt   = (bf16*)(ws + 160 * MB);
  bf16* cc   = (bf16*)(ws + 168 * MB);
  float* ao  = (float*)(ws + 176 * MB); // attn_out, later ff2
  float* h32 = (float*)(ws + 192 * MB);
  bf16* hbf  = (bf16*)(ws + 208 * MB);  // ends at 216MB

  // converts
  k_split_x<<<4096, 256, 0, stream>>>(x, xh, xl);
  k_tcvt<true ><<<dim3(2, 32, 16), 256, 0, stream>>>(wq, wqh, wql, 2048, 128);
  k_tcvt<true ><<<dim3(2, 32, 16), 256, 0, stream>>>(wk, wkh, wkl, 2048, 128);
  k_tcvt<false><<<dim3(2, 32, 16), 256, 0, stream>>>(wv, wvt, nullptr, 2048, 128);
  k_tcvt<false><<<dim3(32, 32, 1), 256, 0, stream>>>(wp, wpt, nullptr, 2048, 2048);
  k_tcvt<false><<<dim3(128, 32, 1), 256, 0, stream>>>(fc1w, fc1t, nullptr, 2048, 8192);
  k_tcvt<false><<<dim3(32, 128, 1), 256, 0, stream>>>(fc2w, fc2t, nullptr, 8192, 2048);

  // Q,K projections (split-precision, scale 1/sqrt(128) folded into Q)
  k_gemm_split3<<<dim3(16, 16), 256, 0, stream>>>(xh, xl, wqh, wql, qh, ql,
                                                  2048, 2048, 2048, 0.08838834764831845f);
  k_gemm_split3<<<dim3(16, 16), 256, 0, stream>>>(xh, xl, wkh, wkl, kh, kl,
                                                  2048, 2048, 2048, 1.0f);
  // V^T directly: C[n][s] = sum_d wvt[n][d] * xh[s][d]
  k_gemm_bt<1><<<dim3(16, 16), 256, 0, stream>>>(wvt, xh, nullptr, vt, nullptr,
                                                 2048, 2048, 2048);
  // attention -> concat
  k_flash<<<dim3(16, 16), 256, 0, stream>>>(qh, ql, kh, kl, vt, cc);
  // out projection
  k_gemm_bt<0><<<dim3(16, 16), 256, 0, stream>>>(cc, wpt, ao, nullptr, nullptr,
                                                 2048, 2048, 2048);
  // h = LN(x + attn_out)
  k_add_ln<<<2048, 256, 0, stream>>>(x, ao, g1, b1, h32, hbf);
  // ff1 = relu(h @ fc1 + b1)
  k_gemm_bt<2><<<dim3(64, 16), 256, 0, stream>>>(hbf, fc1t, nullptr, ff1, fc1b,
                                                 2048, 8192, 2048);
  // ff2 = ff1 @ fc2 + b2 (into ao)
  k_gemm_bt<0><<<dim3(16, 16), 256, 0, stream>>>(ff1, fc2t, ao, nullptr, fc2b,
                                                 2048, 2048, 8192);
  // out = LN(h + ff2)
  k_add_ln<<<2048, 256, 0, stream>>>(h32, ao, g2, b2, out, nullptr);
}

// Round 2
// 579.368 us; speedup vs baseline: 1.5444x; 1.5444x over previous
//
#include <hip/hip_runtime.h>

// TransformerBlock fused pipeline for MI355X (gfx950).
// SEQ=2048, D_MODEL=2048, H=16, DK=DV=128, DFF=8192. fp32 in/out.
//
// Numerics: attention score path (x->Q/K->QK^T) uses 3-pass split-bf16
// (hi/lo). Everything else single-pass bf16 MFMA. LN/softmax/residual fp32.
//
// R2: occupancy fixes. Flash QBLK 128->64 (grid 512, 2 blk/CU). Q,K
// projections fused into one N=4096 split3 GEMM (grid 512). Split-K=2 for
// vt / out-proj / fc2 (grid 512 each), partials combined for free inside
// the residual+LN kernels / a tiny vt combine.

typedef __bf16 bf16;
typedef __attribute__((ext_vector_type(8))) __bf16 bf16x8;
typedef __attribute__((ext_vector_type(4))) __bf16 bf16x4;
typedef __attribute__((ext_vector_type(4))) float f32x4;

#define MFMA(a, b, c) __builtin_amdgcn_mfma_f32_16x16x32_bf16((a), (b), (c), 0, 0, 0)
#define NEG_INF (-3.402823466e38f)

__device__ __forceinline__ void cp16(void* lds, const void* g) {
  __builtin_amdgcn_global_load_lds(
      (const __attribute__((address_space(1))) unsigned int*)g,
      (__attribute__((address_space(3))) unsigned int*)lds, 16, 0, 0);
}

// ---------------- converts ----------------

__global__ void k_split_x(const float* __restrict__ x, bf16* __restrict__ xh,
                          bf16* __restrict__ xl) {
  int i = blockIdx.x * 256 + threadIdx.x;
  f32x4 v = ((const f32x4*)x)[i];
  bf16x4 h, l;
#pragma unroll
  for (int j = 0; j < 4; ++j) {
    bf16 hi = (bf16)v[j];
    h[j] = hi;
    l[j] = (bf16)(v[j] - (float)hi);
  }
  ((bf16x4*)xh)[i] = h;
  ((bf16x4*)xl)[i] = l;
}

// Tiled transpose + convert: in fp32 [R][C] (+z*R*C) -> out bf16 [C][R] (+z*R*C).
template <bool SPLIT>
__global__ void k_tcvt(const float* __restrict__ in, bf16* __restrict__ oh,
                       bf16* __restrict__ ol, int R, int C) {
  __shared__ float t[64][65];
  long zoff = (long)blockIdx.z * R * C;
  int c0 = blockIdx.x * 64, r0 = blockIdx.y * 64;
  int cc = threadIdx.x & 63, rr = threadIdx.x >> 6;
#pragma unroll
  for (int i = 0; i < 16; ++i) {
    int r = i * 4 + rr;
    t[r][cc] = in[zoff + (long)(r0 + r) * C + c0 + cc];
  }
  __syncthreads();
#pragma unroll
  for (int i = 0; i < 16; ++i) {
    int orow = i * 4 + rr;
    float v = t[cc][orow];
    long oidx = zoff + (long)(c0 + orow) * R + r0 + cc;
    bf16 hi = (bf16)v;
    oh[oidx] = hi;
    if (SPLIT) ol[oidx] = (bf16)(v - (float)hi);
  }
}

// combine two fp32 partials -> bf16
__global__ void k_combine_bf16(const float* __restrict__ p0,
                               const float* __restrict__ p1,
                               bf16* __restrict__ o) {
  int i = blockIdx.x * 256 + threadIdx.x;
  f32x4 v = ((const f32x4*)p0)[i] + ((const f32x4*)p1)[i];
  bf16x4 ob;
#pragma unroll
  for (int j = 0; j < 4; ++j) ob[j] = (bf16)v[j];
  ((bf16x4*)o)[i] = ob;
}

// ---------------- GEMM: C[M,N] = A[M,K] @ B[N,K]^T ----------------
// m97 structure: 128x128 tile, BK=32, 4 waves (2x2), global_load_lds w=16.
// Split-K via blockIdx.z (nsplit dispatech slices); EPI0 writes fp32 partial
// at Cf + z*M*N. EPI: 0 = fp32 out (+bias), 2 = relu(v+bias) bf16.
template <int EPI>
__global__ __launch_bounds__(256, 3) void k_gemm_bt(
    const bf16* __restrict__ A, const bf16* __restrict__ B,
    float* __restrict__ Cf, bf16* __restrict__ Cb,
    const float* __restrict__ bias, int M, int N, int K, int nsplit) {
  __shared__ bf16 sA[4096], sB[4096];
  const int tid = threadIdx.x, w = tid >> 6, l = tid & 63;
  const int l16 = l & 15, lg = l >> 4;
  const int wr = w >> 1, wc = w & 1;
  const long bm0 = (long)blockIdx.y * 128, bn0 = (long)blockIdx.x * 128;
  const int z = blockIdx.z;
  const int ks = K / nsplit, kbeg = z * ks, kend = kbeg + ks;
  float* Cfp = (Cf != nullptr) ? Cf + (long)z * M * N : nullptr;
  f32x4 acc[4][4];
#pragma unroll
  for (int m = 0; m < 4; ++m)
#pragma unroll
    for (int n = 0; n < 4; ++n)
#pragma unroll
      for (int j = 0; j < 4; ++j) acc[m][n][j] = 0.f;

  for (int kt = kbeg; kt < kend; kt += 32) {
    __syncthreads();
#pragma unroll
    for (int i = 0; i < 2; ++i) {
      int c = (w * 2 + i) * 64 + l;  // 0..511 chunk of 16B
      int row = c >> 2, seg = c & 3;
      cp16(&sA[(w * 2 + i) * 512], &A[(bm0 + row) * K + kt + seg * 8]);
      cp16(&sB[(w * 2 + i) * 512], &B[(bn0 + row) * K + kt + seg * 8]);
    }
    __syncthreads();
    bf16x8 a[4], b[4];
#pragma unroll
    for (int m = 0; m < 4; ++m)
      a[m] = *(const bf16x8*)&sA[(wr * 64 + m * 16 + l16) * 32 + lg * 8];
#pragma unroll
    for (int n = 0; n < 4; ++n)
      b[n] = *(const bf16x8*)&sB[(wc * 64 + n * 16 + l16) * 32 + lg * 8];
#pragma unroll
    for (int m = 0; m < 4; ++m)
#pragma unroll
      for (int n = 0; n < 4; ++n)
        acc[m][n] = MFMA(a[m], b[n], acc[m][n]);
  }
  // C/D layout col=lane&15, row=(lane>>4)*4+j (m89-verified)
#pragma unroll
  for (int m = 0; m < 4; ++m)
#pragma unroll
    for (int n = 0; n < 4; ++n) {
      long col = bn0 + wc * 64 + n * 16 + l16;
      float bv = (bias != nullptr) ? bias[col] : 0.f;
#pragma unroll
      for (int j = 0; j < 4; ++j) {
        long row = bm0 + wr * 64 + m * 16 + lg * 4 + j;
        float v = acc[m][n][j];
        if (EPI == 0) {
          Cfp[row * N + col] = v + bv;
        } else {
          v = fmaxf(v + bv, 0.f);
          Cb[row * N + col] = (bf16)v;
        }
      }
    }
}

// Split-precision GEMM: C = Ah.Bh^T + Ah.Bl^T + Al.Bh^T, output split hi/lo.
// Per-column scale: col < scale_ncols ? scale : 1 (folds 1/sqrt(dk) into Q).
__global__ __launch_bounds__(256, 2) void k_gemm_split3(
    const bf16* __restrict__ Ah, const bf16* __restrict__ Al,
    const bf16* __restrict__ Bh, const bf16* __restrict__ Bl,
    bf16* __restrict__ Ch, bf16* __restrict__ Cl,
    int M, int N, int K, float scale, int scale_ncols) {
  __shared__ bf16 sAh[4096], sAl[4096], sBh[4096], sBl[4096];
  const int tid = threadIdx.x, w = tid >> 6, l = tid & 63;
  const int l16 = l & 15, lg = l >> 4;
  const int wr = w >> 1, wc = w & 1;
  const long bm0 = (long)blockIdx.y * 128, bn0 = (long)blockIdx.x * 128;
  f32x4 acc[4][4];
#pragma unroll
  for (int m = 0; m < 4; ++m)
#pragma unroll
    for (int n = 0; n < 4; ++n)
#pragma unroll
      for (int j = 0; j < 4; ++j) acc[m][n][j] = 0.f;

  for (int kt = 0; kt < K; kt += 32) {
    __syncthreads();
#pragma unroll
    for (int i = 0; i < 2; ++i) {
      int c = (w * 2 + i) * 64 + l;
      int row = c >> 2, seg = c & 3;
      long ao = (bm0 + row) * K + kt + seg * 8;
      long bo = (bn0 + row) * K + kt + seg * 8;
      int db = (w * 2 + i) * 512;
      cp16(&sAh[db], &Ah[ao]);
      cp16(&sAl[db], &Al[ao]);
      cp16(&sBh[db], &Bh[bo]);
      cp16(&sBl[db], &Bl[bo]);
    }
    __syncthreads();
    bf16x8 ah[4], al[4], bh[4], bl[4];
#pragma unroll
    for (int m = 0; m < 4; ++m) {
      int off = (wr * 64 + m * 16 + l16) * 32 + lg * 8;
      ah[m] = *(const bf16x8*)&sAh[off];
      al[m] = *(const bf16x8*)&sAl[off];
    }
#pragma unroll
    for (int n = 0; n < 4; ++n) {
      int off = (wc * 64 + n * 16 + l16) * 32 + lg * 8;
      bh[n] = *(const bf16x8*)&sBh[off];
      bl[n] = *(const bf16x8*)&sBl[off];
    }
#pragma unroll
    for (int m = 0; m < 4; ++m)
#pragma unroll
      for (int n = 0; n < 4; ++n) {
        acc[m][n] = MFMA(ah[m], bh[n], acc[m][n]);
        acc[m][n] = MFMA(ah[m], bl[n], acc[m][n]);
        acc[m][n] = MFMA(al[m], bh[n], acc[m][n]);
      }
  }
#pragma unroll
  for (int m = 0; m < 4; ++m)
#pragma unroll
    for (int n = 0; n < 4; ++n) {
      long col = bn0 + wc * 64 + n * 16 + l16;
      float sc = (col < scale_ncols) ? scale : 1.0f;
#pragma unroll
      for (int j = 0; j < 4; ++j) {
        long row = bm0 + wr * 64 + m * 16 + lg * 4 + j;
        float v = acc[m][n][j] * sc;
        bf16 hi = (bf16)v;
        Ch[row * N + col] = hi;
        Cl[row * N + col] = (bf16)(v - (float)hi);
      }
    }
}

// ---------------- flash attention ----------------
// Block = (q-block of 64 rows, head). 4 waves, each owns 16 q-rows.
// grid 32x16 = 512 blocks -> 2 blocks/CU (LDS 56KB). Q hi/lo in registers
// (row stride 4096: Q,K fused buffer); K hi/lo + V^T in LDS (XOR-swizzled,
// both-sides). 3-pass QK^T, online softmax fp32, P via LDS, PV MFMA.
__global__ __launch_bounds__(256, 2) void k_flash(
    const bf16* __restrict__ Qh, const bf16* __restrict__ Ql,
    const bf16* __restrict__ Kh, const bf16* __restrict__ Kl,
    const bf16* __restrict__ Vt, bf16* __restrict__ Oc) {
  __shared__ bf16 sm[28672];  // 56KB: Kh[64][128] Kl[64][128] Vt[128][64] P[64][64]
  bf16* sKh = sm;
  bf16* sKl = sm + 8192;
  bf16* sVt = sm + 16384;
  bf16* sP = sm + 24576;
  const int tid = threadIdx.x, w = tid >> 6, l = tid & 63;
  const int l16 = l & 15, lg = l >> 4;
  const int head = blockIdx.y;
  const long q0 = (long)blockIdx.x * 64;

  // Q fragments: rows w*16+l16, k = kk*32+lg*8  (row stride 4096)
  bf16x8 qh_r[4], ql_r[4];
#pragma unroll
  for (int kk = 0; kk < 4; ++kk) {
    long off = (q0 + w * 16 + l16) * 4096 + head * 128 + kk * 32 + lg * 8;
    qh_r[kk] = *(const bf16x8*)&Qh[off];
    ql_r[kk] = *(const bf16x8*)&Ql[off];
  }

  f32x4 acc_o[8];
#pragma unroll
  for (int n = 0; n < 8; ++n)
#pragma unroll
    for (int j = 0; j < 4; ++j) acc_o[n][j] = 0.f;
  float mrow[4], lrow[4];
#pragma unroll
  for (int j = 0; j < 4; ++j) {
    mrow[j] = NEG_INF;
    lrow[j] = 0.f;
  }

  for (int t0 = 0; t0 < 2048; t0 += 64) {
    __syncthreads();
    // stage K hi/lo [64][128] (row stride 4096) and V^T [128][64]
#pragma unroll
    for (int i = 0; i < 4; ++i) {
      int c = (w * 4 + i) * 64 + l;  // 0..1023
      int rk = c >> 4, sk = (c & 15) ^ (rk & 7);
      long ko = (long)(t0 + rk) * 4096 + head * 128 + sk * 8;
      int db = (w * 4 + i) * 512;
      cp16(&sKh[db], &Kh[ko]);
      cp16(&sKl[db], &Kl[ko]);
      int rv = c >> 3, sv = (c & 7) ^ (rv & 7);
      long vo = (long)(head * 128 + rv) * 2048 + t0 + sv * 8;
      cp16(&sVt[db], &Vt[vo]);
    }
    __syncthreads();

    // QK^T, 3-pass split (hi.hi + hi.lo + lo.hi)
    f32x4 s[4];
#pragma unroll
    for (int n = 0; n < 4; ++n)
#pragma unroll
      for (int j = 0; j < 4; ++j) s[n][j] = 0.f;
#pragma unroll
    for (int kk = 0; kk < 4; ++kk) {
      bf16x8 bh[4], bl[4];
#pragma unroll
      for (int n = 0; n < 4; ++n) {
        int r = n * 16 + l16;
        int byo = r * 256 + (((kk * 4 + lg) ^ (r & 7)) << 4);
        bh[n] = *(const bf16x8*)((const char*)sKh + byo);
        bl[n] = *(const bf16x8*)((const char*)sKl + byo);
      }
#pragma unroll
      for (int n = 0; n < 4; ++n) {
        s[n] = MFMA(qh_r[kk], bh[n], s[n]);
        s[n] = MFMA(qh_r[kk], bl[n], s[n]);
        s[n] = MFMA(ql_r[kk], bh[n], s[n]);
      }
    }

    // online softmax: row = w*16 + lg*4 + j, cols = n*16 + l16
#pragma unroll
    for (int j = 0; j < 4; ++j) {
      float mx = fmaxf(fmaxf(s[0][j], s[1][j]), fmaxf(s[2][j], s[3][j]));
      mx = fmaxf(mx, __shfl_xor(mx, 1));
      mx = fmaxf(mx, __shfl_xor(mx, 2));
      mx = fmaxf(mx, __shfl_xor(mx, 4));
      mx = fmaxf(mx, __shfl_xor(mx, 8));
      float mo = mrow[j];
      float mn = fmaxf(mo, mx);
      mrow[j] = mn;
      float f = __expf(mo - mn);
      int prow = w * 16 + lg * 4 + j;
      float ssum = 0.f;
#pragma unroll
      for (int n = 0; n < 4; ++n) {
        float p = __expf(s[n][j] - mn);
        ssum += p;
        int byo = prow * 128 + (((n * 16 + l16) * 2) ^ ((prow & 7) << 4));
        *(bf16*)((char*)sP + byo) = (bf16)p;
      }
      ssum += __shfl_xor(ssum, 1);
      ssum += __shfl_xor(ssum, 2);
      ssum += __shfl_xor(ssum, 4);
      ssum += __shfl_xor(ssum, 8);
      lrow[j] = lrow[j] * f + ssum;
#pragma unroll
      for (int n = 0; n < 8; ++n) acc_o[n][j] *= f;
    }

    // PV: acc_o += P[16s x 64t] @ V[64t x 128v] (per wave; own P rows)
#pragma unroll
    for (int kk = 0; kk < 2; ++kk) {
      bf16x8 pa, bv[8];
      {
        int r = w * 16 + l16;
        int byo = r * 128 + (((kk * 4 + lg) ^ (r & 7)) << 4);
        pa = *(const bf16x8*)((const char*)sP + byo);
      }
#pragma unroll
      for (int n = 0; n < 8; ++n) {
        int r = n * 16 + l16;
        int byo = r * 128 + (((kk * 4 + lg) ^ (r & 7)) << 4);
        bv[n] = *(const bf16x8*)((const char*)sVt + byo);
      }
#pragma unroll
      for (int n = 0; n < 8; ++n)
        acc_o[n] = MFMA(pa, bv[n], acc_o[n]);
    }
  }

  // normalize + write concat[s][head*128 + v]
#pragma unroll
  for (int j = 0; j < 4; ++j) {
    float rinv = 1.f / lrow[j];
    long row = q0 + w * 16 + lg * 4 + j;
#pragma unroll
    for (int n = 0; n < 8; ++n)
      Oc[row * 2048 + head * 128 + n * 16 + l16] = (bf16)(acc_o[n][j] * rinv);
  }
}

// ---------------- residual(+partials) + LayerNorm ----------------
// o = LN(a + b + (c?) + (bias?)); one row (2048) per block.
__global__ __launch_bounds__(256) void k_add_ln(
    const float* __restrict__ a, const float* __restrict__ b,
    const float* __restrict__ c, const float* __restrict__ bias,
    const float* __restrict__ g, const float* __restrict__ be,
    float* __restrict__ o32, bf16* __restrict__ obf) {
  __shared__ float red[8];
  int row = blockIdx.x, tid = threadIdx.x;
  const float* pa = a + (long)row * 2048;
  const float* pb = b + (long)row * 2048;
  const float* pc = (c != nullptr) ? c + (long)row * 2048 : nullptr;
  f32x4 v[2];
  float sum = 0.f, sq = 0.f;
#pragma unroll
  for (int i = 0; i < 2; ++i) {
    int idx = i * 1024 + tid * 4;
    f32x4 va = *(const f32x4*)(pa + idx);
    f32x4 vb = *(const f32x4*)(pb + idx);
    v[i] = va + vb;
    if (pc != nullptr) v[i] += *(const f32x4*)(pc + idx);
    if (bias != nullptr) v[i] += *(const f32x4*)(bias + idx);
#pragma unroll
    for (int j = 0; j < 4; ++j) {
      sum += v[i][j];
      sq += v[i][j] * v[i][j];
    }
  }
#pragma unroll
  for (int o = 1; o < 64; o <<= 1) {
    sum += __shfl_xor(sum, o);
    sq += __shfl_xor(sq, o);
  }
  int w = tid >> 6;
  if ((tid & 63) == 0) {
    red[w * 2] = sum;
    red[w * 2 + 1] = sq;
  }
  __syncthreads();
  sum = red[0] + red[2] + red[4] + red[6];
  sq = red[1] + red[3] + red[5] + red[7];
  float mu = sum * (1.f / 2048.f);
  float var = sq * (1.f / 2048.f) - mu * mu;
  float rs = rsqrtf(var + 1e-5f);
#pragma unroll
  for (int i = 0; i < 2; ++i) {
    int idx = i * 1024 + tid * 4;
    f32x4 vg = *(const f32x4*)(g + idx);
    f32x4 vb = *(const f32x4*)(be + idx);
    f32x4 o;
#pragma unroll
    for (int j = 0; j < 4; ++j) o[j] = (v[i][j] - mu) * rs * vg[j] + vb[j];
    *(f32x4*)(o32 + (long)row * 2048 + idx) = o;
    if (obf != nullptr) {
      bf16x4 ob;
#pragma unroll
      for (int j = 0; j < 4; ++j) ob[j] = (bf16)o[j];
      *(bf16x4*)(obf + (long)row * 2048 + idx) = ob;
    }
  }
}

// ---------------- launch ----------------
extern "C" void kernel_launch(void* const* d_in, const int* in_sizes, int n_in,
                              void* d_out, int out_size, void* d_ws, size_t ws_size,
                              hipStream_t stream) {
  const float* x    = (const float*)d_in[0];
  const float* wq   = (const float*)d_in[1];
  const float* wk   = (const float*)d_in[2];
  const float* wv   = (const float*)d_in[3];
  const float* wp   = (const float*)d_in[4];
  const float* g1   = (const float*)d_in[5];
  const float* b1   = (const float*)d_in[6];
  const float* fc1w = (const float*)d_in[7];
  const float* fc1b = (const float*)d_in[8];
  const float* fc2w = (const float*)d_in[9];
  const float* fc2b = (const float*)d_in[10];
  const float* g2   = (const float*)d_in[11];
  const float* b2   = (const float*)d_in[12];
  float* out = (float*)d_out;

  char* ws = (char*)d_ws;
  const size_t MB = 1024 * 1024;
  if (ws_size < 216 * MB) return;  // need 216MB scratch

  bf16* xh   = (bf16*)(ws + 0 * MB);     // 8MB
  bf16* xl   = (bf16*)(ws + 8 * MB);     // 8MB
  bf16* wqh  = (bf16*)(ws + 16 * MB);    // 8MB  \ adjacent: B-hi [4096][2048]
  bf16* wkh  = (bf16*)(ws + 24 * MB);    // 8MB  /
  bf16* wql  = (bf16*)(ws + 32 * MB);    // 8MB  \ adjacent: B-lo
  bf16* wkl  = (bf16*)(ws + 40 * MB);    // 8MB  /
  bf16* wvt  = (bf16*)(ws + 48 * MB);    // 8MB
  bf16* wpt  = (bf16*)(ws + 56 * MB);    // 8MB
  bf16* fc1t = (bf16*)(ws + 64 * MB);    // 32MB
  bf16* fc2t = (bf16*)(ws + 96 * MB);    // 32MB
  bf16* qkh  = (bf16*)(ws + 128 * MB);   // 16MB [2048][4096]
  bf16* qkl  = (bf16*)(ws + 144 * MB);   // 16MB
  bf16* vt   = (bf16*)(ws + 160 * MB);   // 8MB
  bf16* cc   = (bf16*)(ws + 168 * MB);   // 8MB
  // fp32 partial pairs (time-multiplexed regions):
  float* vtp  = (float*)(ws + 176 * MB); // 2x16MB @176,192 (pre-flash)
  float* aop  = (float*)(ws + 128 * MB); // 2x16MB @128,144 (qk dead post-flash)
  float* ffp  = (float*)(ws + 0 * MB);   // 2x16MB @0,16    (x* dead post-fc1)
  float* h32  = (float*)(ws + 176 * MB); // 16MB (vt partials dead)
  bf16*  hbf  = (bf16*)(ws + 192 * MB);  // 8MB
  bf16*  ff1  = (bf16*)(ws + 128 * MB);  // 32MB (aop dead after LN1)

  // converts
  k_split_x<<<4096, 256, 0, stream>>>(x, xh, xl);
  k_tcvt<true ><<<dim3(2, 32, 16), 256, 0, stream>>>(wq, wqh, wql, 2048, 128);
  k_tcvt<true ><<<dim3(2, 32, 16), 256, 0, stream>>>(wk, wkh, wkl, 2048, 128);
  k_tcvt<false><<<dim3(2, 32, 16), 256, 0, stream>>>(wv, wvt, nullptr, 2048, 128);
  k_tcvt<false><<<dim3(32, 32, 1), 256, 0, stream>>>(wp, wpt, nullptr, 2048, 2048);
  k_tcvt<false><<<dim3(128, 32, 1), 256, 0, stream>>>(fc1w, fc1t, nullptr, 2048, 8192);
  k_tcvt<false><<<dim3(32, 128, 1), 256, 0, stream>>>(fc2w, fc2t, nullptr, 8192, 2048);

  // fused Q,K projection (split-precision), N=4096; 1/sqrt(128) on Q cols
  k_gemm_split3<<<dim3(32, 16), 256, 0, stream>>>(
      xh, xl, wqh, wql, qkh, qkl, 2048, 4096, 2048, 0.08838834764831845f, 2048);
  // V^T: C[v][s] = wvt @ xh^T, split-K=2 -> fp32 partials -> bf16 combine
  k_gemm_bt<0><<<dim3(16, 16, 2), 256, 0, stream>>>(
      wvt, xh, vtp, nullptr, nullptr, 2048, 2048, 2048, 2);
  k_combine_bf16<<<4096, 256, 0, stream>>>(vtp, vtp + 4 * MB, vt);
  // attention -> concat  (Q at cols 0..2047, K at cols 2048..4095)
  k_flash<<<dim3(32, 16), 256, 0, stream>>>(qkh, qkl, qkh + 2048, qkl + 2048,
                                            vt, cc);
  // out projection, split-K=2 (partials combined inside LN1)
  k_gemm_bt<0><<<dim3(16, 16, 2), 256, 0, stream>>>(
      cc, wpt, aop, nullptr, nullptr, 2048, 2048, 2048, 2);
  // h = LN(x + p0 + p1)
  k_add_ln<<<2048, 256, 0, stream>>>(x, aop, aop + 4 * MB, nullptr, g1, b1,
                                     h32, hbf);
  // ff1 = relu(h @ fc1 + b1)
  k_gemm_bt<2><<<dim3(64, 16, 1), 256, 0, stream>>>(
      hbf, fc1t, nullptr, ff1, fc1b, 2048, 8192, 2048, 1);
  // ff2 partials, split-K=2 over K=8192
  k_gemm_bt<0><<<dim3(16, 16, 2), 256, 0, stream>>>(
      ff1, fc2t, ffp, nullptr, nullptr, 2048, 2048, 8192, 2);
  // out = LN(h + p0 + p1 + fc2b)
  k_add_ln<<<2048, 256, 0, stream>>>(h32, ffp, ffp + 4 * MB, fc2b, g2, b2,
                                     out, nullptr);
}